// Round 8
// baseline (754.080 us; speedup 1.0000x reference)
//
#include <hip/hip_runtime.h>
#include <math.h>

// Problem constants (from reference)
#define Nn 50000
#define MPAD 50048  // Nn padded to multiple of 128 (GEMM row tiles, no guards)
#define Ee 500000
#define Cc 256
#define Hh 128
#define Ll 4
#define Gg 64
#define Kk 8
#define NCc 2

#define NB 196  // ceil(Nn/256)

typedef __attribute__((ext_vector_type(8))) short short8;
typedef __attribute__((ext_vector_type(4))) float f32x4;
typedef __attribute__((ext_vector_type(2))) float f32x2;

__device__ __forceinline__ unsigned short f2bf(float f) {
    union { float f; unsigned int u; } v;
    v.f = f;
    unsigned int u = v.u;
    return (unsigned short)((u + 0x7FFFu + ((u >> 16) & 1u)) >> 16);
}
__device__ __forceinline__ float bf2f(unsigned short s) {
    union { float f; unsigned int u; } v;
    v.u = ((unsigned int)s) << 16;
    return v.f;
}
__device__ __forceinline__ float bf2f_lo(unsigned int u) {
    union { float f; unsigned int u; } v;
    v.u = u << 16;
    return v.f;
}
__device__ __forceinline__ float bf2f_hi(unsigned int u) {
    union { float f; unsigned int u; } v;
    v.u = u & 0xffff0000u;
    return v.f;
}

// ---------------- CSR build ----------------

__global__ void hist_kernel(const int* __restrict__ dst, int* __restrict__ deg) {
    int e = blockIdx.x * 256 + threadIdx.x;
    if (e < Ee) atomicAdd(&deg[dst[e]], 1);
}

__global__ __launch_bounds__(256) void bsum_kernel(const int* __restrict__ deg,
                                                   int* __restrict__ bsum) {
    __shared__ int ws[4];
    int t = threadIdx.x;
    int i = blockIdx.x * 256 + t;
    int v = (i < Nn) ? deg[i] : 0;
#pragma unroll
    for (int o = 32; o; o >>= 1) v += __shfl_down(v, o, 64);
    if ((t & 63) == 0) ws[t >> 6] = v;
    __syncthreads();
    if (t == 0) bsum[blockIdx.x] = ws[0] + ws[1] + ws[2] + ws[3];
}

__global__ __launch_bounds__(256) void bscan_kernel(const int* __restrict__ bsum,
                                                    int* __restrict__ boff,
                                                    int* __restrict__ off) {
    __shared__ int sc[256];
    int t = threadIdx.x;
    int v = (t < NB) ? bsum[t] : 0;
    sc[t] = v;
    __syncthreads();
    for (int o = 1; o < 256; o <<= 1) {
        int u = (t >= o) ? sc[t - o] : 0;
        __syncthreads();
        sc[t] += u;
        __syncthreads();
    }
    if (t < NB) boff[t] = sc[t] - v;  // exclusive
    if (t == NB - 1) off[Nn] = sc[t];
}

__global__ __launch_bounds__(256) void offsets_kernel(const int* __restrict__ deg,
                                                      const int* __restrict__ boff,
                                                      int* __restrict__ off,
                                                      int* __restrict__ pos) {
    __shared__ int sc[256];
    int t = threadIdx.x;
    int i = blockIdx.x * 256 + t;
    int v = (i < Nn) ? deg[i] : 0;
    sc[t] = v;
    __syncthreads();
    for (int o = 1; o < 256; o <<= 1) {
        int u = (t >= o) ? sc[t - o] : 0;
        __syncthreads();
        sc[t] += u;
        __syncthreads();
    }
    int excl = sc[t] - v + boff[blockIdx.x];
    if (i < Nn) {
        off[i] = excl;
        pos[i] = excl;
    }
}

__global__ void scatter_kernel(const int* __restrict__ src, const int* __restrict__ dst,
                               const float* __restrict__ attr, int* __restrict__ pos,
                               int2* __restrict__ sedge) {
    int e = blockIdx.x * 256 + threadIdx.x;
    if (e < Ee) {
        int d = dst[e];
        int p = atomicAdd(&pos[d], 1);
        sedge[p] = make_int2(src[e], __float_as_int(attr[e]));
    }
}

// ---------------- weight convert + transpose to bf16 [N][K] ----------------
// wt layout: [0, 65536)            proj  [256 n][256 k]  (n<128: lin_src col, else lin_dst)
//            [65536, 196608)       w1[l] [256 n][128 k]
//            [196608, 327680)      w2[l] [128 n][256 k]

__global__ void wconv_kernel(const float* __restrict__ lin_src_w,
                             const float* __restrict__ lin_dst_w,
                             const float* __restrict__ mlp_w1,
                             const float* __restrict__ mlp_w2,
                             unsigned short* __restrict__ wt) {
    int idx = blockIdx.x * 256 + threadIdx.x;
    if (idx >= 327680) return;
    float val;
    if (idx < 65536) {
        int n = idx >> 8, k = idx & 255;
        val = (n < 128) ? lin_src_w[k * 128 + n] : lin_dst_w[k * 128 + (n - 128)];
    } else if (idx < 196608) {
        int r = idx - 65536;
        int l = r >> 15, e = r & 32767;
        int n = e >> 7, k = e & 127;
        val = mlp_w1[(size_t)l * 32768 + k * 256 + n];
    } else {
        int r = idx - 196608;
        int l = r >> 15, e = r & 32767;
        int n = e >> 8, k = e & 255;
        val = mlp_w2[(size_t)l * 32768 + k * 128 + n];
    }
    wt[idx] = f2bf(val);
}

// ---------------- x fp32 -> bf16 (one-time, vectorized) ----------------

__global__ __launch_bounds__(256) void xconv_kernel(const float* __restrict__ x,
                                                    unsigned short* __restrict__ xbf) {
    int idx = blockIdx.x * 256 + threadIdx.x;  // 8 elems per thread
    if (idx >= (Nn * Cc) / 8) return;
    const float4* p = (const float4*)(x) + (size_t)idx * 2;
    float4 v0 = p[0], v1 = p[1];
    unsigned short t[8];
    t[0] = f2bf(v0.x); t[1] = f2bf(v0.y); t[2] = f2bf(v0.z); t[3] = f2bf(v0.w);
    t[4] = f2bf(v1.x); t[5] = f2bf(v1.y); t[6] = f2bf(v1.z); t[7] = f2bf(v1.w);
    *(short8*)(xbf + (size_t)idx * 8) = *(short8*)t;
}

#define GLOAD16(gp, lp)                                                                       \
    __builtin_amdgcn_global_load_lds(                                                         \
        (const __attribute__((address_space(1))) unsigned int*)(gp),                          \
        (__attribute__((address_space(3))) unsigned int*)(lp), 16, 0, 0)

// ---------------- projection GEMM: xsd = x @ [Wsrc|Wdst] + [bsrc|bdst] ----------------
// 128x128 tile, BK=32, 4 waves, depth-2 prefetch (3 LDS buffers, counted vmcnt).
// Epilogue staged through LDS -> coalesced short8 stores.

__global__ __launch_bounds__(256) void proj_kernel(
    const unsigned short* __restrict__ A, const unsigned short* __restrict__ Bt,
    const float* __restrict__ bias, const float* __restrict__ bias2,
    unsigned short* __restrict__ Cout) {
    __shared__ __align__(16) unsigned short SH[24576];  // 48KB: 3xA(8KB) + 3xB(8KB); C reuse
    int tid = threadIdx.x;
    int wave = tid >> 6, lane = tid & 63;
    int wr = wave >> 1, wc = wave & 1;
    int lrow = lane & 15, quad = lane >> 4;
    int m0 = blockIdx.y * 128, n0 = blockIdx.x * 128;
    const int K = 256;

    const unsigned short* ag0 = A + (size_t)(m0 + (tid >> 2)) * K + (tid & 3) * 8;
    const unsigned short* ag1 = A + (size_t)(m0 + 64 + (tid >> 2)) * K + (tid & 3) * 8;
    const unsigned short* bg0 = Bt + (size_t)(n0 + (tid >> 2)) * K + (tid & 3) * 8;
    const unsigned short* bg1 = Bt + (size_t)(n0 + 64 + (tid >> 2)) * K + (tid & 3) * 8;

    f32x4 acc[4][4];
#pragma unroll
    for (int i = 0; i < 4; i++)
#pragma unroll
        for (int j = 0; j < 4; j++) acc[i][j] = (f32x4){0.f, 0.f, 0.f, 0.f};

    auto stage = [&](int buf, int koff) {
        GLOAD16(ag0 + koff, SH + buf * 4096 + wave * 512);
        GLOAD16(ag1 + koff, SH + buf * 4096 + 2048 + wave * 512);
        GLOAD16(bg0 + koff, SH + 12288 + buf * 4096 + wave * 512);
        GLOAD16(bg1 + koff, SH + 12288 + buf * 4096 + 2048 + wave * 512);
    };

    const int ntiles = 8;
    stage(0, 0);
    stage(1, 32);
    for (int t = 0; t < ntiles; ++t) {
        if (t + 1 < ntiles) {
            asm volatile("s_waitcnt vmcnt(4)\n\ts_barrier" ::: "memory");
        } else {
            asm volatile("s_waitcnt vmcnt(0)\n\ts_barrier" ::: "memory");
        }
        if (t + 2 < ntiles) stage((t + 2) % 3, (t + 2) * 32);
        int cur = t % 3;
        const unsigned short* As = SH + cur * 4096;
        const unsigned short* Bs = SH + 12288 + cur * 4096;
        short8 af[4], bfr[4];
#pragma unroll
        for (int mt = 0; mt < 4; mt++)
            af[mt] = *(const short8*)&As[(wr * 64 + mt * 16 + lrow) * 32 + quad * 8];
#pragma unroll
        for (int nf = 0; nf < 4; nf++)
            bfr[nf] = *(const short8*)&Bs[(wc * 64 + nf * 16 + lrow) * 32 + quad * 8];
#pragma unroll
        for (int mt = 0; mt < 4; mt++)
#pragma unroll
            for (int nf = 0; nf < 4; nf++)
                acc[mt][nf] = __builtin_amdgcn_mfma_f32_16x16x32_bf16(af[mt], bfr[nf],
                                                                     acc[mt][nf], 0, 0, 0);
    }

    __syncthreads();  // all frag reads done; reuse SH for C tile
    unsigned short* Cl = SH;  // [128][128] bf16 = 32KB
#pragma unroll
    for (int nf = 0; nf < 4; nf++) {
        int gc = n0 + wc * 64 + nf * 16 + lrow;
        float bs = (gc >= 128) ? bias2[gc - 128] : bias[gc];
        int col = wc * 64 + nf * 16 + lrow;
#pragma unroll
        for (int mt = 0; mt < 4; mt++)
#pragma unroll
            for (int r = 0; r < 4; r++)
                Cl[(wr * 64 + mt * 16 + quad * 4 + r) * 128 + col] = f2bf(acc[mt][nf][r] + bs);
    }
    __syncthreads();
#pragma unroll
    for (int p = 0; p < 8; p++) {
        int vid = p * 256 + tid;
        int row = vid >> 4, cg = (vid & 15) * 8;
        short8 v = *(const short8*)&Cl[row * 128 + cg];
        *(short8*)(Cout + (size_t)(m0 + row) * 256 + n0 + cg) = v;
    }
}

// ---------------- fully-fused GENConv layer ----------------
// Per 64-node block: phase 0 = edge aggregation (agg + skip) -> LDS Agg tile
// (never HBM); phase 1 = Agg @ W1 -> BN -> ReLU -> LDS Hm; phase 2 = Hm @ W2
// + b2 -> residual RMW on hbuf + next-layer prenorm -> rout.
// W1/W2 B-fragments read directly from global (64KB each, L2-resident across
// all 782 blocks).  LDS 50KB -> 3 blocks/CU: co-resident blocks sit in
// different phases, so agg-VALU overlaps MFMA (m114).  rbuf double-buffered
// across layers (this kernel READS rin via random gather and WRITES rout).
// CSR guard: pad nodes (d >= Nn) get s0=s1=0 -- off[] only has Nn+1 entries
// (round-6 crash: pad nodes read past off[] -> wild gathers -> fault).

#define AGP 136   // Agg row pad: 272B = 16B-aligned, 2-way banks
#define HMP 264   // Hm row pad:  528B = 16B-aligned, 2-way banks
#define C2P 132   // C2 fp32 row pad

template <int XSS>
__global__ __launch_bounds__(256) void layer_kernel(
    const unsigned short* __restrict__ xs,
    const unsigned short* __restrict__ xd, int xds,
    const int2* __restrict__ sedge, const int* __restrict__ off,
    const float* __restrict__ ew, const float* __restrict__ eb,
    const float* __restrict__ tptr,
    const unsigned short* __restrict__ W1,   // [256 n][128 k] bf16
    const unsigned short* __restrict__ W2,   // [128 n][256 k] bf16
    const float* __restrict__ b1, const float* __restrict__ bn_g,
    const float* __restrict__ bn_b, const float* __restrict__ bn_m,
    const float* __restrict__ bn_v, const float* __restrict__ b2,
    const float* __restrict__ pn_g, const float* __restrict__ pn_b,
    const float* __restrict__ pn_m, const float* __restrict__ pn_v,
    float* __restrict__ hbuf, unsigned short* __restrict__ rout, int rmw) {
    __shared__ __align__(16) unsigned short Agg[64 * AGP];  // 17.4KB
    __shared__ __align__(16) unsigned short Hm[64 * HMP];   // 33.8KB (C2 fp32 reuse)

    int tid = threadIdx.x;
    int wave = tid >> 6, lane = tid & 63;
    int lrow = lane & 15, quad = lane >> 4;
    int m0 = blockIdx.x * 64;

    // ---- phase 0: aggregation for 16 nodes per wave, 2 features per lane ----
    {
        int f0 = lane * 2;
        f32x2 wv = *(const f32x2*)(ew + f0);
        f32x2 bv = *(const f32x2*)(eb + f0);
        float cc = tptr[0] * 1.44269504088896f;
        const f32x2 zz = {0.f, 0.f};
        const f32x2 ee = {1e-7f, 1e-7f};
#define EDGE2(u, av)                                                      \
    {                                                                     \
        f32x2 xv = {bf2f_lo(u), bf2f_hi(u)};                              \
        f32x2 m = __builtin_elementwise_max(xv + bv + (av)*wv, zz) + ee;  \
        f32x2 e;                                                          \
        e.x = __builtin_amdgcn_exp2f(m.x * cc);                           \
        e.y = __builtin_amdgcn_exp2f(m.y * cc);                           \
        den += e;                                                         \
        num += m * e;                                                     \
    }
        for (int nn = 0; nn < 16; nn++) {
            int d = m0 + wave * 16 + nn;
            int s0 = 0, s1 = 0;
            if (d < Nn) {  // pad nodes have no CSR entries (off[] has Nn+1 elems)
                s0 = off[d];
                s1 = off[d + 1];
            }
            f32x2 den = {0.f, 0.f}, num = {0.f, 0.f};
            int j = s0;
            for (; j + 3 < s1; j += 4) {
                int2 p0 = sedge[j], p1 = sedge[j + 1], p2 = sedge[j + 2], p3 = sedge[j + 3];
                unsigned int u0 = *(const unsigned int*)(xs + (size_t)p0.x * XSS + f0);
                unsigned int u1 = *(const unsigned int*)(xs + (size_t)p1.x * XSS + f0);
                unsigned int u2 = *(const unsigned int*)(xs + (size_t)p2.x * XSS + f0);
                unsigned int u3 = *(const unsigned int*)(xs + (size_t)p3.x * XSS + f0);
                EDGE2(u0, __int_as_float(p0.y))
                EDGE2(u1, __int_as_float(p1.y))
                EDGE2(u2, __int_as_float(p2.y))
                EDGE2(u3, __int_as_float(p3.y))
            }
            for (; j < s1; j++) {
                int2 p = sedge[j];
                unsigned int u = *(const unsigned int*)(xs + (size_t)p.x * XSS + f0);
                EDGE2(u, __int_as_float(p.y))
            }
            float a0 = (s1 > s0) ? (num.x / fmaxf(den.x, 1e-16f)) : 0.f;
            float a1 = (s1 > s0) ? (num.y / fmaxf(den.y, 1e-16f)) : 0.f;
            unsigned int ud = *(const unsigned int*)(xd + (size_t)d * xds + f0);
            unsigned int lo = f2bf(a0 + bf2f_lo(ud));
            unsigned int hi = f2bf(a1 + bf2f_hi(ud));
            *(unsigned int*)&Agg[(wave * 16 + nn) * AGP + f0] = lo | (hi << 16);
        }
#undef EDGE2
    }
    __syncthreads();  // Agg complete

    // ---- phase 1: Hm = relu(BN(Agg @ W1 + b1))  (64x256); B direct from L2 ----
    f32x4 acc1[4][4];
#pragma unroll
    for (int i = 0; i < 4; i++)
#pragma unroll
        for (int j = 0; j < 4; j++) acc1[i][j] = (f32x4){0.f, 0.f, 0.f, 0.f};
#pragma unroll
    for (int t = 0; t < 4; t++) {
        short8 af[4], bfr[4];
#pragma unroll
        for (int mt = 0; mt < 4; mt++)
            af[mt] = *(const short8*)&Agg[(mt * 16 + lrow) * AGP + t * 32 + quad * 8];
#pragma unroll
        for (int nf = 0; nf < 4; nf++)
            bfr[nf] = *(const short8*)(W1 + (size_t)(wave * 64 + nf * 16 + lrow) * 128 +
                                       t * 32 + quad * 8);
#pragma unroll
        for (int mt = 0; mt < 4; mt++)
#pragma unroll
            for (int nf = 0; nf < 4; nf++)
                acc1[mt][nf] = __builtin_amdgcn_mfma_f32_16x16x32_bf16(af[mt], bfr[nf],
                                                                      acc1[mt][nf], 0, 0, 0);
    }
#pragma unroll
    for (int nf = 0; nf < 4; nf++) {
        int gc = wave * 64 + nf * 16 + lrow;
        float bs = b1[gc];
        float g = bn_g[gc], bb = bn_b[gc], mm = bn_m[gc];
        float inv = rsqrtf(bn_v[gc] + 1e-5f);
#pragma unroll
        for (int mt = 0; mt < 4; mt++)
#pragma unroll
            for (int r = 0; r < 4; r++) {
                float v = acc1[mt][nf][r] + bs;
                v = fmaxf(g * (v - mm) * inv + bb, 0.f);
                Hm[(mt * 16 + quad * 4 + r) * HMP + gc] = f2bf(v);
            }
    }
    __syncthreads();  // Hm complete

    // ---- phase 2: C2 = Hm @ W2 + b2  (64x128); B direct from L2 ----
    f32x4 acc2[4][2];
#pragma unroll
    for (int i = 0; i < 4; i++)
#pragma unroll
        for (int j = 0; j < 2; j++) acc2[i][j] = (f32x4){0.f, 0.f, 0.f, 0.f};
#pragma unroll
    for (int t = 0; t < 8; t++) {
        short8 af[4], bfr[2];
#pragma unroll
        for (int mt = 0; mt < 4; mt++)
            af[mt] = *(const short8*)&Hm[(mt * 16 + lrow) * HMP + t * 32 + quad * 8];
#pragma unroll
        for (int nf = 0; nf < 2; nf++)
            bfr[nf] = *(const short8*)(W2 + (size_t)(wave * 32 + nf * 16 + lrow) * 256 +
                                       t * 32 + quad * 8);
#pragma unroll
        for (int mt = 0; mt < 4; mt++)
#pragma unroll
            for (int nf = 0; nf < 2; nf++)
                acc2[mt][nf] = __builtin_amdgcn_mfma_f32_16x16x32_bf16(af[mt], bfr[nf],
                                                                      acc2[mt][nf], 0, 0, 0);
    }
    __syncthreads();  // all Hm reads done; reuse as fp32 C2

    float* C2 = (float*)Hm;  // [64][C2P] fp32
#pragma unroll
    for (int nf = 0; nf < 2; nf++) {
        int gc = wave * 32 + nf * 16 + lrow;
        float bs = b2[gc];
#pragma unroll
        for (int mt = 0; mt < 4; mt++)
#pragma unroll
            for (int r = 0; r < 4; r++)
                C2[(mt * 16 + quad * 4 + r) * C2P + gc] = acc2[mt][nf][r] + bs;
    }
    __syncthreads();
#pragma unroll
    for (int p = 0; p < 8; p++) {
        int vid = p * 256 + tid;
        int row = vid >> 5, c4 = (vid & 31) * 4;
        f32x4 v = *(const f32x4*)&C2[row * C2P + c4];
        float* hp = hbuf + (size_t)(m0 + row) * 128 + c4;
        if (rmw) v += *(const f32x4*)hp;
        *(f32x4*)hp = v;
        if (pn_g) {
            f32x4 pg = *(const f32x4*)&pn_g[c4];
            f32x4 pb = *(const f32x4*)&pn_b[c4];
            f32x4 pm = *(const f32x4*)&pn_m[c4];
            f32x4 pv = *(const f32x4*)&pn_v[c4];
            float r0 = fmaxf(pg[0] * (v[0] - pm[0]) * rsqrtf(pv[0] + 1e-5f) + pb[0], 0.f);
            float r1 = fmaxf(pg[1] * (v[1] - pm[1]) * rsqrtf(pv[1] + 1e-5f) + pb[1], 0.f);
            float r2 = fmaxf(pg[2] * (v[2] - pm[2]) * rsqrtf(pv[2] + 1e-5f) + pb[2], 0.f);
            float r3 = fmaxf(pg[3] * (v[3] - pm[3]) * rsqrtf(pv[3] + 1e-5f) + pb[3], 0.f);
            unsigned int w0 = (unsigned int)f2bf(r0) | ((unsigned int)f2bf(r1) << 16);
            unsigned int w1 = (unsigned int)f2bf(r2) | ((unsigned int)f2bf(r3) << 16);
            uint2 pk = make_uint2(w0, w1);
            *(uint2*)(rout + (size_t)(m0 + row) * 128 + c4) = pk;
        }
    }
}

// ---------------- final norm + hierarchical mean-pool ----------------

#define PCHUNK 100

__global__ __launch_bounds__(128) void pool_kernel(
    const float* __restrict__ h, const int* __restrict__ batch,
    const float* __restrict__ g, const float* __restrict__ b,
    const float* __restrict__ m, const float* __restrict__ v,
    float* __restrict__ pooled, float* __restrict__ cnt) {
    int hh = threadIdx.x;
    int i0 = blockIdx.x * PCHUNK;
    int i1 = min(i0 + PCHUNK, Nn);
    if (i0 >= Nn) return;
    float gg = g[hh], bb = b[hh], mm = m[hh], inv = rsqrtf(v[hh] + 1e-5f);
    int cur = batch[i0];
    float sum = 0.f, c = 0.f;
    for (int i = i0; i < i1; i++) {
        int gid = batch[i];
        float val = fmaxf(gg * (h[(size_t)i * Hh + hh] - mm) * inv + bb, 0.f);
        if (gid != cur) {
            atomicAdd(&pooled[(size_t)cur * Hh + hh], sum);
            if (hh == 0) atomicAdd(&cnt[cur], c);
            cur = gid;
            sum = 0.f;
            c = 0.f;
        }
        sum += val;
        c += 1.f;
    }
    atomicAdd(&pooled[(size_t)cur * Hh + hh], sum);
    if (hh == 0) atomicAdd(&cnt[cur], c);
}

// ---------------- classifier ----------------

__global__ __launch_bounds__(128) void cls_kernel(const float* __restrict__ pooled,
                                                  const float* __restrict__ cnt,
                                                  const float* __restrict__ clinical,
                                                  const float* __restrict__ w,
                                                  const float* __restrict__ bias,
                                                  float* __restrict__ out) {
    int t = threadIdx.x;
    int g = t >> 1, c = t & 1;
    float inv = 1.f / fmaxf(cnt[g], 1.f);
    float s = bias[c];
    for (int j = 0; j < Hh; j++) s += pooled[g * Hh + j] * inv * w[j * NCc + c];
    for (int k = 0; k < Kk; k++) s += clinical[g * Kk + k] * w[(Hh + k) * NCc + c];
    out[g * NCc + c] = s;
}

// ---------------- launch ----------------

extern "C" void kernel_launch(void* const* d_in, const int* in_sizes, int n_in,
                              void* d_out, int out_size, void* d_ws, size_t ws_size,
                              hipStream_t stream) {
    const float* x = (const float*)d_in[0];
    const int* eidx = (const int*)d_in[1];
    const float* eattr = (const float*)d_in[2];
    const int* batch = (const int*)d_in[3];
    const float* clinical = (const float*)d_in[4];
    const float* lin_src_w = (const float*)d_in[5];
    const float* lin_src_b = (const float*)d_in[6];
    const float* lin_dst_w = (const float*)d_in[7];
    const float* lin_dst_b = (const float*)d_in[8];
    const float* edge_w = (const float*)d_in[9];
    const float* edge_b = (const float*)d_in[10];
    const float* tt = (const float*)d_in[11];
    const float* mlp_w1 = (const float*)d_in[12];
    const float* mlp_b1 = (const float*)d_in[13];
    const float* bn_g = (const float*)d_in[14];
    const float* bn_b = (const float*)d_in[15];
    const float* bn_m = (const float*)d_in[16];
    const float* bn_v = (const float*)d_in[17];
    const float* mlp_w2 = (const float*)d_in[18];
    const float* mlp_b2 = (const float*)d_in[19];
    const float* norm_g = (const float*)d_in[20];
    const float* norm_b = (const float*)d_in[21];
    const float* norm_m = (const float*)d_in[22];
    const float* norm_v = (const float*)d_in[23];
    const float* cls_w = (const float*)d_in[24];
    const float* cls_b = (const float*)d_in[25];
    float* out = (float*)d_out;

    const int* src = eidx;
    const int* dst = eidx + Ee;

    char* ws = (char*)d_ws;
    size_t off_b = 0;
    auto alloc = [&](size_t bytes) -> void* {
        void* p = ws + off_b;
        off_b += (bytes + 255) & ~(size_t)255;
        return p;
    };
    // All GEMM-touched buffers padded to MPAD rows (garbage pad rows never read).
    unsigned short* xsd = (unsigned short*)alloc((size_t)MPAD * 256 * 2);   // proj out
    unsigned short* rb0 = (unsigned short*)alloc((size_t)MPAD * Hh * 2);    // prenorm dbuf
    unsigned short* rb1 = (unsigned short*)alloc((size_t)MPAD * Hh * 2);
    unsigned short* xbf = (unsigned short*)alloc((size_t)MPAD * 256 * 2);
    float* hbuf = (float*)alloc((size_t)MPAD * Hh * 4);
    int* deg = (int*)alloc((Nn + 1) * 4);
    int* offp = (int*)alloc((Nn + 1) * 4);
    int* pos = (int*)alloc((size_t)Nn * 4);
    int* bsum = (int*)alloc(NB * 4);
    int* boff = (int*)alloc(NB * 4);
    int2* sedge = (int2*)alloc((size_t)Ee * 8);
    float* pooled = (float*)alloc((size_t)Gg * Hh * 4);
    float* cntb = (float*)alloc(Gg * 4);
    unsigned short* wt = (unsigned short*)alloc((size_t)327680 * 2);

    hipMemsetAsync(deg, 0, (Nn + 1) * 4, stream);
    hipMemsetAsync(pooled, 0, (size_t)Gg * Hh * 4, stream);
    hipMemsetAsync(cntb, 0, Gg * 4, stream);

    hist_kernel<<<(Ee + 255) / 256, 256, 0, stream>>>(dst, deg);
    bsum_kernel<<<NB, 256, 0, stream>>>(deg, bsum);
    bscan_kernel<<<1, 256, 0, stream>>>(bsum, boff, offp);
    offsets_kernel<<<NB, 256, 0, stream>>>(deg, boff, offp, pos);
    scatter_kernel<<<(Ee + 255) / 256, 256, 0, stream>>>(src, dst, eattr, pos, sedge);
    wconv_kernel<<<1280, 256, 0, stream>>>(lin_src_w, lin_dst_w, mlp_w1, mlp_w2, wt);
    xconv_kernel<<<(Nn * Cc / 8 + 255) / 256, 256, 0, stream>>>(x, xbf);

    const unsigned short* wt_proj = wt;
    const unsigned short* wt_w1 = wt + 65536;
    const unsigned short* wt_w2 = wt + 196608;

    // Fused projection: xsd[:, :128] = x@Wsrc+b, xsd[:, 128:] = x@Wdst+b
    dim3 gproj(2, MPAD / 128);
    proj_kernel<<<gproj, 256, 0, stream>>>(xbf, wt_proj, lin_src_b, lin_dst_b, xsd);

    // rbuf double-buffer: layer l reads rin (produced by l-1), writes rout.
    unsigned short* rb[2] = {rb0, rb1};
    for (int l = 0; l < Ll; l++) {
        const float* png = (l < Ll - 1) ? (norm_g + (l + 1) * Hh) : nullptr;
        const float* pnb = (l < Ll - 1) ? (norm_b + (l + 1) * Hh) : nullptr;
        const float* pnm = (l < Ll - 1) ? (norm_m + (l + 1) * Hh) : nullptr;
        const float* pnv = (l < Ll - 1) ? (norm_v + (l + 1) * Hh) : nullptr;
        unsigned short* rout = rb[l & 1];
        const unsigned short* rin = rb[1 - (l & 1)];
        if (l == 0) {
            layer_kernel<256><<<MPAD / 64, 256, 0, stream>>>(
                xsd, xsd + 128, 256, sedge, offp, edge_w, edge_b, tt,
                wt_w1, wt_w2, mlp_b1, bn_g, bn_b, bn_m, bn_v, mlp_b2,
                png, pnb, pnm, pnv, hbuf, rout, 0);
        } else {
            layer_kernel<128><<<MPAD / 64, 256, 0, stream>>>(
                rin, rin, 128, sedge, offp, edge_w + l * Hh, edge_b + l * Hh, tt + l,
                wt_w1 + (size_t)l * 32768, wt_w2 + (size_t)l * 32768,
                mlp_b1 + l * 2 * Hh, bn_g + l * 2 * Hh, bn_b + l * 2 * Hh,
                bn_m + l * 2 * Hh, bn_v + l * 2 * Hh, mlp_b2 + l * Hh,
                png, pnb, pnm, pnv, hbuf, rout, 1);
        }
    }

    pool_kernel<<<(Nn + PCHUNK - 1) / PCHUNK, 128, 0, stream>>>(hbuf, batch, norm_g, norm_b,
                                                                norm_m, norm_v, pooled, cntb);
    cls_kernel<<<1, 128, 0, stream>>>(pooled, cntb, clinical, cls_w, cls_b, out);
}

// Round 9
// 508.033 us; speedup vs baseline: 1.4843x; 1.4843x over previous
//
#include <hip/hip_runtime.h>
#include <math.h>

// Problem constants (from reference)
#define Nn 50000
#define MPAD 50048  // Nn padded to multiple of 128 (GEMM row tiles, no guards)
#define Ee 500000
#define Cc 256
#define Hh 128
#define Ll 4
#define Gg 64
#define Kk 8
#define NCc 2

#define NB 196  // ceil(Nn/256)

typedef __attribute__((ext_vector_type(8))) short short8;
typedef __attribute__((ext_vector_type(4))) float f32x4;
typedef __attribute__((ext_vector_type(2))) float f32x2;

__device__ __forceinline__ unsigned short f2bf(float f) {
    union { float f; unsigned int u; } v;
    v.f = f;
    unsigned int u = v.u;
    return (unsigned short)((u + 0x7FFFu + ((u >> 16) & 1u)) >> 16);
}
__device__ __forceinline__ float bf2f(unsigned short s) {
    union { float f; unsigned int u; } v;
    v.u = ((unsigned int)s) << 16;
    return v.f;
}
__device__ __forceinline__ float bf2f_lo(unsigned int u) {
    union { float f; unsigned int u; } v;
    v.u = u << 16;
    return v.f;
}
__device__ __forceinline__ float bf2f_hi(unsigned int u) {
    union { float f; unsigned int u; } v;
    v.u = u & 0xffff0000u;
    return v.f;
}

// ---------------- CSR build ----------------

__global__ void hist_kernel(const int* __restrict__ dst, int* __restrict__ deg) {
    int e = blockIdx.x * 256 + threadIdx.x;
    if (e < Ee) atomicAdd(&deg[dst[e]], 1);
}

__global__ __launch_bounds__(256) void bsum_kernel(const int* __restrict__ deg,
                                                   int* __restrict__ bsum) {
    __shared__ int ws[4];
    int t = threadIdx.x;
    int i = blockIdx.x * 256 + t;
    int v = (i < Nn) ? deg[i] : 0;
#pragma unroll
    for (int o = 32; o; o >>= 1) v += __shfl_down(v, o, 64);
    if ((t & 63) == 0) ws[t >> 6] = v;
    __syncthreads();
    if (t == 0) bsum[blockIdx.x] = ws[0] + ws[1] + ws[2] + ws[3];
}

__global__ __launch_bounds__(256) void bscan_kernel(const int* __restrict__ bsum,
                                                    int* __restrict__ boff,
                                                    int* __restrict__ off) {
    __shared__ int sc[256];
    int t = threadIdx.x;
    int v = (t < NB) ? bsum[t] : 0;
    sc[t] = v;
    __syncthreads();
    for (int o = 1; o < 256; o <<= 1) {
        int u = (t >= o) ? sc[t - o] : 0;
        __syncthreads();
        sc[t] += u;
        __syncthreads();
    }
    if (t < NB) boff[t] = sc[t] - v;  // exclusive
    if (t == NB - 1) off[Nn] = sc[t];
}

__global__ __launch_bounds__(256) void offsets_kernel(const int* __restrict__ deg,
                                                      const int* __restrict__ boff,
                                                      int* __restrict__ off,
                                                      int* __restrict__ pos) {
    __shared__ int sc[256];
    int t = threadIdx.x;
    int i = blockIdx.x * 256 + t;
    int v = (i < Nn) ? deg[i] : 0;
    sc[t] = v;
    __syncthreads();
    for (int o = 1; o < 256; o <<= 1) {
        int u = (t >= o) ? sc[t - o] : 0;
        __syncthreads();
        sc[t] += u;
        __syncthreads();
    }
    int excl = sc[t] - v + boff[blockIdx.x];
    if (i < Nn) {
        off[i] = excl;
        pos[i] = excl;
    }
}

__global__ void scatter_kernel(const int* __restrict__ src, const int* __restrict__ dst,
                               const float* __restrict__ attr, int* __restrict__ pos,
                               int2* __restrict__ sedge) {
    int e = blockIdx.x * 256 + threadIdx.x;
    if (e < Ee) {
        int d = dst[e];
        int p = atomicAdd(&pos[d], 1);
        sedge[p] = make_int2(src[e], __float_as_int(attr[e]));
    }
}

// ---------------- weight convert + transpose to bf16 [N][K] ----------------
// wt layout: [0, 65536)            proj  [256 n][256 k]  (n<128: lin_src col, else lin_dst)
//            [65536, 196608)       w1[l] [256 n][128 k]
//            [196608, 327680)      w2[l] [128 n][256 k]

__global__ void wconv_kernel(const float* __restrict__ lin_src_w,
                             const float* __restrict__ lin_dst_w,
                             const float* __restrict__ mlp_w1,
                             const float* __restrict__ mlp_w2,
                             unsigned short* __restrict__ wt) {
    int idx = blockIdx.x * 256 + threadIdx.x;
    if (idx >= 327680) return;
    float val;
    if (idx < 65536) {
        int n = idx >> 8, k = idx & 255;
        val = (n < 128) ? lin_src_w[k * 128 + n] : lin_dst_w[k * 128 + (n - 128)];
    } else if (idx < 196608) {
        int r = idx - 65536;
        int l = r >> 15, e = r & 32767;
        int n = e >> 7, k = e & 127;
        val = mlp_w1[(size_t)l * 32768 + k * 256 + n];
    } else {
        int r = idx - 196608;
        int l = r >> 15, e = r & 32767;
        int n = e >> 8, k = e & 255;
        val = mlp_w2[(size_t)l * 32768 + k * 128 + n];
    }
    wt[idx] = f2bf(val);
}

// ---------------- x fp32 -> bf16 (one-time, vectorized) ----------------

__global__ __launch_bounds__(256) void xconv_kernel(const float* __restrict__ x,
                                                    unsigned short* __restrict__ xbf) {
    int idx = blockIdx.x * 256 + threadIdx.x;  // 8 elems per thread
    if (idx >= (Nn * Cc) / 8) return;
    const float4* p = (const float4*)(x) + (size_t)idx * 2;
    float4 v0 = p[0], v1 = p[1];
    unsigned short t[8];
    t[0] = f2bf(v0.x); t[1] = f2bf(v0.y); t[2] = f2bf(v0.z); t[3] = f2bf(v0.w);
    t[4] = f2bf(v1.x); t[5] = f2bf(v1.y); t[6] = f2bf(v1.z); t[7] = f2bf(v1.w);
    *(short8*)(xbf + (size_t)idx * 8) = *(short8*)t;
}

#define GLOAD16(gp, lp)                                                                       \
    __builtin_amdgcn_global_load_lds(                                                         \
        (const __attribute__((address_space(1))) unsigned int*)(gp),                          \
        (__attribute__((address_space(3))) unsigned int*)(lp), 16, 0, 0)

// ---------------- projection GEMM: xsd = x @ [Wsrc|Wdst] + [bsrc|bdst] ----------------
// 128x128 tile, BK=32, 4 waves, depth-2 prefetch (3 LDS buffers, counted vmcnt).
// Epilogue staged through LDS -> coalesced short8 stores.

__global__ __launch_bounds__(256) void proj_kernel(
    const unsigned short* __restrict__ A, const unsigned short* __restrict__ Bt,
    const float* __restrict__ bias, const float* __restrict__ bias2,
    unsigned short* __restrict__ Cout) {
    __shared__ __align__(16) unsigned short SH[24576];  // 48KB: 3xA(8KB) + 3xB(8KB); C reuse
    int tid = threadIdx.x;
    int wave = tid >> 6, lane = tid & 63;
    int wr = wave >> 1, wc = wave & 1;
    int lrow = lane & 15, quad = lane >> 4;
    int m0 = blockIdx.y * 128, n0 = blockIdx.x * 128;
    const int K = 256;

    const unsigned short* ag0 = A + (size_t)(m0 + (tid >> 2)) * K + (tid & 3) * 8;
    const unsigned short* ag1 = A + (size_t)(m0 + 64 + (tid >> 2)) * K + (tid & 3) * 8;
    const unsigned short* bg0 = Bt + (size_t)(n0 + (tid >> 2)) * K + (tid & 3) * 8;
    const unsigned short* bg1 = Bt + (size_t)(n0 + 64 + (tid >> 2)) * K + (tid & 3) * 8;

    f32x4 acc[4][4];
#pragma unroll
    for (int i = 0; i < 4; i++)
#pragma unroll
        for (int j = 0; j < 4; j++) acc[i][j] = (f32x4){0.f, 0.f, 0.f, 0.f};

    auto stage = [&](int buf, int koff) {
        GLOAD16(ag0 + koff, SH + buf * 4096 + wave * 512);
        GLOAD16(ag1 + koff, SH + buf * 4096 + 2048 + wave * 512);
        GLOAD16(bg0 + koff, SH + 12288 + buf * 4096 + wave * 512);
        GLOAD16(bg1 + koff, SH + 12288 + buf * 4096 + 2048 + wave * 512);
    };

    const int ntiles = 8;
    stage(0, 0);
    stage(1, 32);
    for (int t = 0; t < ntiles; ++t) {
        if (t + 1 < ntiles) {
            asm volatile("s_waitcnt vmcnt(4)\n\ts_barrier" ::: "memory");
        } else {
            asm volatile("s_waitcnt vmcnt(0)\n\ts_barrier" ::: "memory");
        }
        if (t + 2 < ntiles) stage((t + 2) % 3, (t + 2) * 32);
        int cur = t % 3;
        const unsigned short* As = SH + cur * 4096;
        const unsigned short* Bs = SH + 12288 + cur * 4096;
        short8 af[4], bfr[4];
#pragma unroll
        for (int mt = 0; mt < 4; mt++)
            af[mt] = *(const short8*)&As[(wr * 64 + mt * 16 + lrow) * 32 + quad * 8];
#pragma unroll
        for (int nf = 0; nf < 4; nf++)
            bfr[nf] = *(const short8*)&Bs[(wc * 64 + nf * 16 + lrow) * 32 + quad * 8];
#pragma unroll
        for (int mt = 0; mt < 4; mt++)
#pragma unroll
            for (int nf = 0; nf < 4; nf++)
                acc[mt][nf] = __builtin_amdgcn_mfma_f32_16x16x32_bf16(af[mt], bfr[nf],
                                                                     acc[mt][nf], 0, 0, 0);
    }

    __syncthreads();  // all frag reads done; reuse SH for C tile
    unsigned short* Cl = SH;  // [128][128] bf16 = 32KB
#pragma unroll
    for (int nf = 0; nf < 4; nf++) {
        int gc = n0 + wc * 64 + nf * 16 + lrow;
        float bs = (gc >= 128) ? bias2[gc - 128] : bias[gc];
        int col = wc * 64 + nf * 16 + lrow;
#pragma unroll
        for (int mt = 0; mt < 4; mt++)
#pragma unroll
            for (int r = 0; r < 4; r++)
                Cl[(wr * 64 + mt * 16 + quad * 4 + r) * 128 + col] = f2bf(acc[mt][nf][r] + bs);
    }
    __syncthreads();
#pragma unroll
    for (int p = 0; p < 8; p++) {
        int vid = p * 256 + tid;
        int row = vid >> 4, cg = (vid & 15) * 8;
        short8 v = *(const short8*)&Cl[row * 128 + cg];
        *(short8*)(Cout + (size_t)(m0 + row) * 256 + n0 + cg) = v;
    }
}

// ---------------- fused per-layer MLP: hbuf (+)= agg @ W1 -> BN -> ReLU -> @ W2 + b2,
//                  plus next-layer prenorm rbuf = bf16(relu(BN_pn(hbuf))) ----------------
// Per 64-node tile: phase 1 writes hmid to LDS only (never HBM); phase 2 consumes it.

__global__ __launch_bounds__(256) void mlp_kernel(
    const unsigned short* __restrict__ A,    // aggout [MPAD][128] bf16
    const unsigned short* __restrict__ W1,   // [256 n][128 k] bf16
    const unsigned short* __restrict__ W2,   // [128 n][256 k] bf16
    const float* __restrict__ b1, const float* __restrict__ bn_g,
    const float* __restrict__ bn_b, const float* __restrict__ bn_m,
    const float* __restrict__ bn_v, const float* __restrict__ b2,
    const float* __restrict__ pn_g, const float* __restrict__ pn_b,
    const float* __restrict__ pn_m, const float* __restrict__ pn_v,
    float* __restrict__ hbuf, unsigned short* __restrict__ rbuf, int rmw) {
    __shared__ __align__(16) unsigned short S[20480];    // 40KB: A1 dbuf 2x4KB @0, B1 dbuf 2x16KB @8KB
    __shared__ __align__(16) unsigned short Hm[64 * 264];  // hmid, padded rows (16B-aligned)

    int tid = threadIdx.x;
    int wave = tid >> 6, lane = tid & 63;
    int lrow = lane & 15, quad = lane >> 4;
    int m0 = blockIdx.x * 64;

    // ---- phase 1: Hm = relu(BN(A[m0:m0+64] @ W1 + b1))  (64x256) ----
    const unsigned short* ag = A + (size_t)(m0 + (tid >> 2)) * 128 + (tid & 3) * 8;
    const unsigned short* bg = W1 + (size_t)(tid >> 2) * 128 + (tid & 3) * 8;

    f32x4 acc1[4][4];
#pragma unroll
    for (int i = 0; i < 4; i++)
#pragma unroll
        for (int j = 0; j < 4; j++) acc1[i][j] = (f32x4){0.f, 0.f, 0.f, 0.f};

    auto stage1 = [&](int buf, int k0) {
        GLOAD16(ag + k0, S + buf * 2048 + wave * 512);
#pragma unroll
        for (int c = 0; c < 4; c++)
            GLOAD16(bg + (size_t)c * 64 * 128 + k0,
                    S + 4096 + buf * 8192 + c * 2048 + wave * 512);
    };

    stage1(0, 0);
    __syncthreads();
    for (int t = 0; t < 4; ++t) {
        if (t + 1 < 4) stage1((t + 1) & 1, (t + 1) * 32);
        int cur = t & 1;
        const unsigned short* A1s = S + cur * 2048;
        const unsigned short* B1s = S + 4096 + cur * 8192;
        short8 af[4], bfr[4];
#pragma unroll
        for (int mt = 0; mt < 4; mt++)
            af[mt] = *(const short8*)&A1s[(mt * 16 + lrow) * 32 + quad * 8];
#pragma unroll
        for (int nf = 0; nf < 4; nf++)
            bfr[nf] = *(const short8*)&B1s[(wave * 64 + nf * 16 + lrow) * 32 + quad * 8];
#pragma unroll
        for (int mt = 0; mt < 4; mt++)
#pragma unroll
            for (int nf = 0; nf < 4; nf++)
                acc1[mt][nf] = __builtin_amdgcn_mfma_f32_16x16x32_bf16(af[mt], bfr[nf],
                                                                      acc1[mt][nf], 0, 0, 0);
        __syncthreads();
    }

    // epilogue 1 -> Hm (LDS only)
#pragma unroll
    for (int nf = 0; nf < 4; nf++) {
        int gc = wave * 64 + nf * 16 + lrow;
        float bs = b1[gc];
        float g = bn_g[gc], bb = bn_b[gc], mm = bn_m[gc];
        float inv = rsqrtf(bn_v[gc] + 1e-5f);
#pragma unroll
        for (int mt = 0; mt < 4; mt++)
#pragma unroll
            for (int r = 0; r < 4; r++) {
                float v = acc1[mt][nf][r] + bs;
                v = fmaxf(g * (v - mm) * inv + bb, 0.f);
                Hm[(mt * 16 + quad * 4 + r) * 264 + gc] = f2bf(v);
            }
    }
    __syncthreads();  // Hm complete; phase-1 staging region free

    // ---- phase 2: C2 = Hm @ W2 + b2  (64x128) ----
    const unsigned short* b2g0 = W2 + (size_t)(tid >> 2) * 256 + (tid & 3) * 8;
    const unsigned short* b2g1 = W2 + (size_t)(64 + (tid >> 2)) * 256 + (tid & 3) * 8;

    f32x4 acc2[4][2];
#pragma unroll
    for (int i = 0; i < 4; i++)
#pragma unroll
        for (int j = 0; j < 2; j++) acc2[i][j] = (f32x4){0.f, 0.f, 0.f, 0.f};

    auto stage2 = [&](int buf, int k0) {
        GLOAD16(b2g0 + k0, S + buf * 4096 + wave * 512);
        GLOAD16(b2g1 + k0, S + buf * 4096 + 2048 + wave * 512);
    };

    stage2(0, 0);
    __syncthreads();
    for (int t = 0; t < 8; ++t) {
        if (t + 1 < 8) stage2((t + 1) & 1, (t + 1) * 32);
        int cur = t & 1;
        const unsigned short* B2s = S + cur * 4096;
        short8 af[4], bfr[2];
#pragma unroll
        for (int mt = 0; mt < 4; mt++)
            af[mt] = *(const short8*)&Hm[(mt * 16 + lrow) * 264 + t * 32 + quad * 8];
#pragma unroll
        for (int nf = 0; nf < 2; nf++)
            bfr[nf] = *(const short8*)&B2s[(wave * 32 + nf * 16 + lrow) * 32 + quad * 8];
#pragma unroll
        for (int mt = 0; mt < 4; mt++)
#pragma unroll
            for (int nf = 0; nf < 2; nf++)
                acc2[mt][nf] = __builtin_amdgcn_mfma_f32_16x16x32_bf16(af[mt], bfr[nf],
                                                                      acc2[mt][nf], 0, 0, 0);
        __syncthreads();
    }

    // epilogue 2: stage fp32 C2 in LDS (over staging region), then coalesced writeback
    float* C2 = (float*)S;  // [64][128] fp32 = 32KB
#pragma unroll
    for (int nf = 0; nf < 2; nf++) {
        int gc = wave * 32 + nf * 16 + lrow;
        float bs = b2[gc];
#pragma unroll
        for (int mt = 0; mt < 4; mt++)
#pragma unroll
            for (int r = 0; r < 4; r++)
                C2[(mt * 16 + quad * 4 + r) * 128 + gc] = acc2[mt][nf][r] + bs;
    }
    __syncthreads();
#pragma unroll
    for (int p = 0; p < 8; p++) {
        int vid = p * 256 + tid;
        int row = vid >> 5, c4 = (vid & 31) * 4;
        f32x4 v = *(const f32x4*)&C2[row * 128 + c4];
        float* hp = hbuf + (size_t)(m0 + row) * 128 + c4;
        if (rmw) v += *(const f32x4*)hp;
        *(f32x4*)hp = v;
        if (pn_g) {
            f32x4 pg = *(const f32x4*)&pn_g[c4];
            f32x4 pb = *(const f32x4*)&pn_b[c4];
            f32x4 pm = *(const f32x4*)&pn_m[c4];
            f32x4 pv = *(const f32x4*)&pn_v[c4];
            float r0 = fmaxf(pg[0] * (v[0] - pm[0]) * rsqrtf(pv[0] + 1e-5f) + pb[0], 0.f);
            float r1 = fmaxf(pg[1] * (v[1] - pm[1]) * rsqrtf(pv[1] + 1e-5f) + pb[1], 0.f);
            float r2 = fmaxf(pg[2] * (v[2] - pm[2]) * rsqrtf(pv[2] + 1e-5f) + pb[2], 0.f);
            float r3 = fmaxf(pg[3] * (v[3] - pm[3]) * rsqrtf(pv[3] + 1e-5f) + pb[3], 0.f);
            unsigned int w0 = (unsigned int)f2bf(r0) | ((unsigned int)f2bf(r1) << 16);
            unsigned int w1 = (unsigned int)f2bf(r2) | ((unsigned int)f2bf(r3) << 16);
            uint2 pk = make_uint2(w0, w1);
            *(uint2*)(rbuf + (size_t)(m0 + row) * 128 + c4) = pk;
        }
    }
}

// ---------------- Fused GENConv aggregation ----------------
// One wave per dst node, 2 features per lane.  8-deep unrolled edge batches:
// 8 independent gathers in flight (edge meta via int4), masked final batch
// (index clamped to last valid edge -> L1-hit broadcast, contribution x0)
// eliminates the serial remainder tail that dominated the latency chain.
// Softmax shift-invariance (z = msg*t, msg>0, t~0.1) -> no online-max needed.

template <int XSS>
__global__ __launch_bounds__(256) void agg_kernel(
    const unsigned short* __restrict__ xs,
    const unsigned short* __restrict__ xd, int xds,
    const int2* __restrict__ sedge, const int* __restrict__ off,
    const float* __restrict__ ew, const float* __restrict__ eb,
    const float* __restrict__ tptr, unsigned short* __restrict__ outb) {
    int wave = threadIdx.x >> 6;
    int lane = threadIdx.x & 63;
    int d = blockIdx.x * 4 + wave;  // Nn % 4 == 0, always < Nn
    int s0 = off[d], s1 = off[d + 1];
    int f0 = lane * 2;
    unsigned int ud = *(const unsigned int*)(xd + (size_t)d * xds + f0);  // hoisted
    f32x2 wv = *(const f32x2*)(ew + f0);
    f32x2 bv = *(const f32x2*)(eb + f0);
    float c = tptr[0] * 1.44269504088896f;  // fold t and log2(e) into exp2 scale
    const f32x2 zz = {0.f, 0.f};
    const f32x2 ee = {1e-7f, 1e-7f};
    f32x2 den = {0.f, 0.f}, num = {0.f, 0.f};

#define EDGE2(u, av)                                                      \
    {                                                                     \
        f32x2 xv = {bf2f_lo(u), bf2f_hi(u)};                              \
        f32x2 m = __builtin_elementwise_max(xv + bv + (av)*wv, zz) + ee;  \
        f32x2 e;                                                          \
        e.x = __builtin_amdgcn_exp2f(m.x * c);                            \
        e.y = __builtin_amdgcn_exp2f(m.y * c);                            \
        den += e;                                                         \
        num += m * e;                                                     \
    }
#define EDGE2M(u, av, mk)                                                 \
    {                                                                     \
        f32x2 xv = {bf2f_lo(u), bf2f_hi(u)};                              \
        f32x2 m = __builtin_elementwise_max(xv + bv + (av)*wv, zz) + ee;  \
        f32x2 e;                                                          \
        e.x = __builtin_amdgcn_exp2f(m.x * c) * (mk);                     \
        e.y = __builtin_amdgcn_exp2f(m.y * c) * (mk);                     \
        den += e;                                                         \
        num += m * e;                                                     \
    }

    int j = s0;
    for (; j + 8 <= s1; j += 8) {
        // edge meta: 4x int4 = 8 (src, attr) pairs, one dwordx4 each
        int4 q0 = *(const int4*)(sedge + j);
        int4 q1 = *(const int4*)(sedge + j + 2);
        int4 q2 = *(const int4*)(sedge + j + 4);
        int4 q3 = *(const int4*)(sedge + j + 6);
        unsigned int u0 = *(const unsigned int*)(xs + (size_t)q0.x * XSS + f0);
        unsigned int u1 = *(const unsigned int*)(xs + (size_t)q0.z * XSS + f0);
        unsigned int u2 = *(const unsigned int*)(xs + (size_t)q1.x * XSS + f0);
        unsigned int u3 = *(const unsigned int*)(xs + (size_t)q1.z * XSS + f0);
        unsigned int u4 = *(const unsigned int*)(xs + (size_t)q2.x * XSS + f0);
        unsigned int u5 = *(const unsigned int*)(xs + (size_t)q2.z * XSS + f0);
        unsigned int u6 = *(const unsigned int*)(xs + (size_t)q3.x * XSS + f0);
        unsigned int u7 = *(const unsigned int*)(xs + (size_t)q3.z * XSS + f0);
        EDGE2(u0, __int_as_float(q0.y))
        EDGE2(u1, __int_as_float(q0.w))
        EDGE2(u2, __int_as_float(q1.y))
        EDGE2(u3, __int_as_float(q1.w))
        EDGE2(u4, __int_as_float(q2.y))
        EDGE2(u5, __int_as_float(q2.w))
        EDGE2(u6, __int_as_float(q3.y))
        EDGE2(u7, __int_as_float(q3.w))
    }
    if (j < s1) {  // masked batch: clamp to last valid edge, zero masked lanes
        int last = s1 - 1;  // s1 > s0 >= 0 here
        int ii[8];
        float aa[8], mk[8];
#pragma unroll
        for (int k = 0; k < 8; k++) {
            int jj = j + k;
            int cl = (jj < s1) ? jj : last;
            int2 p = sedge[cl];
            ii[k] = p.x;
            aa[k] = __int_as_float(p.y);
            mk[k] = (jj < s1) ? 1.f : 0.f;
        }
        unsigned int uu[8];
#pragma unroll
        for (int k = 0; k < 8; k++)
            uu[k] = *(const unsigned int*)(xs + (size_t)ii[k] * XSS + f0);
#pragma unroll
        for (int k = 0; k < 8; k++) EDGE2M(uu[k], aa[k], mk[k])
    }
#undef EDGE2
#undef EDGE2M
    float a0 = (s1 > s0) ? (num.x / fmaxf(den.x, 1e-16f)) : 0.f;
    float a1 = (s1 > s0) ? (num.y / fmaxf(den.y, 1e-16f)) : 0.f;
    unsigned int lo = f2bf(a0 + bf2f_lo(ud));
    unsigned int hi = f2bf(a1 + bf2f_hi(ud));
    *(unsigned int*)(outb + (size_t)d * Hh + f0) = lo | (hi << 16);
}

// ---------------- final norm + hierarchical mean-pool ----------------

#define PCHUNK 100

__global__ __launch_bounds__(128) void pool_kernel(
    const float* __restrict__ h, const int* __restrict__ batch,
    const float* __restrict__ g, const float* __restrict__ b,
    const float* __restrict__ m, const float* __restrict__ v,
    float* __restrict__ pooled, float* __restrict__ cnt) {
    int hh = threadIdx.x;
    int i0 = blockIdx.x * PCHUNK;
    int i1 = min(i0 + PCHUNK, Nn);
    if (i0 >= Nn) return;
    float gg = g[hh], bb = b[hh], mm = m[hh], inv = rsqrtf(v[hh] + 1e-5f);
    int cur = batch[i0];
    float sum = 0.f, c = 0.f;
    for (int i = i0; i < i1; i++) {
        int gid = batch[i];
        float val = fmaxf(gg * (h[(size_t)i * Hh + hh] - mm) * inv + bb, 0.f);
        if (gid != cur) {
            atomicAdd(&pooled[(size_t)cur * Hh + hh], sum);
            if (hh == 0) atomicAdd(&cnt[cur], c);
            cur = gid;
            sum = 0.f;
            c = 0.f;
        }
        sum += val;
        c += 1.f;
    }
    atomicAdd(&pooled[(size_t)cur * Hh + hh], sum);
    if (hh == 0) atomicAdd(&cnt[cur], c);
}

// ---------------- classifier ----------------

__global__ __launch_bounds__(128) void cls_kernel(const float* __restrict__ pooled,
                                                  const float* __restrict__ cnt,
                                                  const float* __restrict__ clinical,
                                                  const float* __restrict__ w,
                                                  const float* __restrict__ bias,
                                                  float* __restrict__ out) {
    int t = threadIdx.x;
    int g = t >> 1, c = t & 1;
    float inv = 1.f / fmaxf(cnt[g], 1.f);
    float s = bias[c];
    for (int j = 0; j < Hh; j++) s += pooled[g * Hh + j] * inv * w[j * NCc + c];
    for (int k = 0; k < Kk; k++) s += clinical[g * Kk + k] * w[(Hh + k) * NCc + c];
    out[g * NCc + c] = s;
}

// ---------------- launch ----------------

extern "C" void kernel_launch(void* const* d_in, const int* in_sizes, int n_in,
                              void* d_out, int out_size, void* d_ws, size_t ws_size,
                              hipStream_t stream) {
    const float* x = (const float*)d_in[0];
    const int* eidx = (const int*)d_in[1];
    const float* eattr = (const float*)d_in[2];
    const int* batch = (const int*)d_in[3];
    const float* clinical = (const float*)d_in[4];
    const float* lin_src_w = (const float*)d_in[5];
    const float* lin_src_b = (const float*)d_in[6];
    const float* lin_dst_w = (const float*)d_in[7];
    const float* lin_dst_b = (const float*)d_in[8];
    const float* edge_w = (const float*)d_in[9];
    const float* edge_b = (const float*)d_in[10];
    const float* tt = (const float*)d_in[11];
    const float* mlp_w1 = (const float*)d_in[12];
    const float* mlp_b1 = (const float*)d_in[13];
    const float* bn_g = (const float*)d_in[14];
    const float* bn_b = (const float*)d_in[15];
    const float* bn_m = (const float*)d_in[16];
    const float* bn_v = (const float*)d_in[17];
    const float* mlp_w2 = (const float*)d_in[18];
    const float* mlp_b2 = (const float*)d_in[19];
    const float* norm_g = (const float*)d_in[20];
    const float* norm_b = (const float*)d_in[21];
    const float* norm_m = (const float*)d_in[22];
    const float* norm_v = (const float*)d_in[23];
    const float* cls_w = (const float*)d_in[24];
    const float* cls_b = (const float*)d_in[25];
    float* out = (float*)d_out;

    const int* src = eidx;
    const int* dst = eidx + Ee;

    char* ws = (char*)d_ws;
    size_t off_b = 0;
    auto alloc = [&](size_t bytes) -> void* {
        void* p = ws + off_b;
        off_b += (bytes + 255) & ~(size_t)255;
        return p;
    };
    // All GEMM-touched buffers padded to MPAD rows (garbage pad rows never read).
    unsigned short* xsd = (unsigned short*)alloc((size_t)MPAD * 256 * 2);   // proj out
    unsigned short* rbuf = (unsigned short*)alloc((size_t)MPAD * Hh * 2);   // prenorm out
    unsigned short* aggout = (unsigned short*)alloc((size_t)MPAD * Hh * 2);
    unsigned short* xbf = (unsigned short*)alloc((size_t)MPAD * 256 * 2);
    float* hbuf = (float*)alloc((size_t)MPAD * Hh * 4);
    int* deg = (int*)alloc((Nn + 1) * 4);
    int* offp = (int*)alloc((Nn + 1) * 4);
    int* pos = (int*)alloc((size_t)Nn * 4);
    int* bsum = (int*)alloc(NB * 4);
    int* boff = (int*)alloc(NB * 4);
    int2* sedge = (int2*)alloc((size_t)Ee * 8);
    float* pooled = (float*)alloc((size_t)Gg * Hh * 4);
    float* cntb = (float*)alloc(Gg * 4);
    unsigned short* wt = (unsigned short*)alloc((size_t)327680 * 2);

    hipMemsetAsync(deg, 0, (Nn + 1) * 4, stream);
    hipMemsetAsync(pooled, 0, (size_t)Gg * Hh * 4, stream);
    hipMemsetAsync(cntb, 0, Gg * 4, stream);

    hist_kernel<<<(Ee + 255) / 256, 256, 0, stream>>>(dst, deg);
    bsum_kernel<<<NB, 256, 0, stream>>>(deg, bsum);
    bscan_kernel<<<1, 256, 0, stream>>>(bsum, boff, offp);
    offsets_kernel<<<NB, 256, 0, stream>>>(deg, boff, offp, pos);
    scatter_kernel<<<(Ee + 255) / 256, 256, 0, stream>>>(src, dst, eattr, pos, sedge);
    wconv_kernel<<<1280, 256, 0, stream>>>(lin_src_w, lin_dst_w, mlp_w1, mlp_w2, wt);
    xconv_kernel<<<(Nn * Cc / 8 + 255) / 256, 256, 0, stream>>>(x, xbf);

    const unsigned short* wt_proj = wt;
    const unsigned short* wt_w1 = wt + 65536;
    const unsigned short* wt_w2 = wt + 196608;

    // Fused projection: xsd[:, :128] = x@Wsrc+b, xsd[:, 128:] = x@Wdst+b
    dim3 gproj(2, MPAD / 128);
    proj_kernel<<<gproj, 256, 0, stream>>>(xbf, wt_proj, lin_src_b, lin_dst_b, xsd);

    for (int l = 0; l < Ll; l++) {
        if (l == 0) {
            agg_kernel<256><<<Nn / 4, 256, 0, stream>>>(xsd, xsd + 128, 256, sedge, offp,
                                                        edge_w + l * Hh, edge_b + l * Hh,
                                                        tt + l, aggout);
        } else {
            agg_kernel<128><<<Nn / 4, 256, 0, stream>>>(rbuf, rbuf, Hh, sedge, offp,
                                                        edge_w + l * Hh, edge_b + l * Hh,
                                                        tt + l, aggout);
        }
        const float* png = (l < Ll - 1) ? (norm_g + (l + 1) * Hh) : nullptr;
        const float* pnb = (l < Ll - 1) ? (norm_b + (l + 1) * Hh) : nullptr;
        const float* pnm = (l < Ll - 1) ? (norm_m + (l + 1) * Hh) : nullptr;
        const float* pnv = (l < Ll - 1) ? (norm_v + (l + 1) * Hh) : nullptr;
        mlp_kernel<<<MPAD / 64, 256, 0, stream>>>(
            aggout, wt_w1 + (size_t)l * 32768, wt_w2 + (size_t)l * 32768,
            mlp_b1 + l * 2 * Hh, bn_g + l * 2 * Hh, bn_b + l * 2 * Hh,
            bn_m + l * 2 * Hh, bn_v + l * 2 * Hh, mlp_b2 + l * Hh,
            png, pnb, pnm, pnv, hbuf, rbuf, (l == 0) ? 0 : 1);
    }

    pool_kernel<<<(Nn + PCHUNK - 1) / PCHUNK, 128, 0, stream>>>(hbuf, batch, norm_g, norm_b,
                                                                norm_m, norm_v, pooled, cntb);
    cls_kernel<<<1, 128, 0, stream>>>(pooled, cntb, clinical, cls_w, cls_b, out);
}

// Round 10
// 483.692 us; speedup vs baseline: 1.5590x; 1.0503x over previous
//
#include <hip/hip_runtime.h>
#include <math.h>

// Problem constants (from reference)
#define Nn 50000
#define MPAD 50048  // Nn padded to multiple of 128 (GEMM row tiles, no guards)
#define Ee 500000
#define Cc 256
#define Hh 128
#define Ll 4
#define Gg 64
#define Kk 8
#define NCc 2

#define NB 196  // ceil(Nn/256)

typedef __attribute__((ext_vector_type(8))) short short8;
typedef __attribute__((ext_vector_type(4))) float f32x4;
typedef __attribute__((ext_vector_type(2))) float f32x2;

__device__ __forceinline__ unsigned short f2bf(float f) {
    union { float f; unsigned int u; } v;
    v.f = f;
    unsigned int u = v.u;
    return (unsigned short)((u + 0x7FFFu + ((u >> 16) & 1u)) >> 16);
}
__device__ __forceinline__ float bf2f(unsigned short s) {
    union { float f; unsigned int u; } v;
    v.u = ((unsigned int)s) << 16;
    return v.f;
}
__device__ __forceinline__ float bf2f_lo(unsigned int u) {
    union { float f; unsigned int u; } v;
    v.u = u << 16;
    return v.f;
}
__device__ __forceinline__ float bf2f_hi(unsigned int u) {
    union { float f; unsigned int u; } v;
    v.u = u & 0xffff0000u;
    return v.f;
}

// ---------------- CSR build ----------------

__global__ void hist_kernel(const int* __restrict__ dst, int* __restrict__ deg) {
    int e = blockIdx.x * 256 + threadIdx.x;
    if (e < Ee) atomicAdd(&deg[dst[e]], 1);
}

__global__ __launch_bounds__(256) void bsum_kernel(const int* __restrict__ deg,
                                                   int* __restrict__ bsum) {
    __shared__ int ws[4];
    int t = threadIdx.x;
    int i = blockIdx.x * 256 + t;
    int v = (i < Nn) ? deg[i] : 0;
#pragma unroll
    for (int o = 32; o; o >>= 1) v += __shfl_down(v, o, 64);
    if ((t & 63) == 0) ws[t >> 6] = v;
    __syncthreads();
    if (t == 0) bsum[blockIdx.x] = ws[0] + ws[1] + ws[2] + ws[3];
}

__global__ __launch_bounds__(256) void bscan_kernel(const int* __restrict__ bsum,
                                                    int* __restrict__ boff,
                                                    int* __restrict__ off) {
    __shared__ int sc[256];
    int t = threadIdx.x;
    int v = (t < NB) ? bsum[t] : 0;
    sc[t] = v;
    __syncthreads();
    for (int o = 1; o < 256; o <<= 1) {
        int u = (t >= o) ? sc[t - o] : 0;
        __syncthreads();
        sc[t] += u;
        __syncthreads();
    }
    if (t < NB) boff[t] = sc[t] - v;  // exclusive
    if (t == NB - 1) off[Nn] = sc[t];
}

__global__ __launch_bounds__(256) void offsets_kernel(const int* __restrict__ deg,
                                                      const int* __restrict__ boff,
                                                      int* __restrict__ off,
                                                      int* __restrict__ pos) {
    __shared__ int sc[256];
    int t = threadIdx.x;
    int i = blockIdx.x * 256 + t;
    int v = (i < Nn) ? deg[i] : 0;
    sc[t] = v;
    __syncthreads();
    for (int o = 1; o < 256; o <<= 1) {
        int u = (t >= o) ? sc[t - o] : 0;
        __syncthreads();
        sc[t] += u;
        __syncthreads();
    }
    int excl = sc[t] - v + boff[blockIdx.x];
    if (i < Nn) {
        off[i] = excl;
        pos[i] = excl;
    }
}

__global__ void scatter_kernel(const int* __restrict__ src, const int* __restrict__ dst,
                               const float* __restrict__ attr, int* __restrict__ pos,
                               int2* __restrict__ sedge) {
    int e = blockIdx.x * 256 + threadIdx.x;
    if (e < Ee) {
        int d = dst[e];
        int p = atomicAdd(&pos[d], 1);
        sedge[p] = make_int2(src[e], __float_as_int(attr[e]));
    }
}

// ---------------- weight convert + transpose to bf16 [N][K] ----------------
// wt layout: [0, 65536)            proj  [256 n][256 k]  (n<128: lin_src col, else lin_dst)
//            [65536, 196608)       w1[l] [256 n][128 k]
//            [196608, 327680)      w2[l] [128 n][256 k]

__global__ void wconv_kernel(const float* __restrict__ lin_src_w,
                             const float* __restrict__ lin_dst_w,
                             const float* __restrict__ mlp_w1,
                             const float* __restrict__ mlp_w2,
                             unsigned short* __restrict__ wt) {
    int idx = blockIdx.x * 256 + threadIdx.x;
    if (idx >= 327680) return;
    float val;
    if (idx < 65536) {
        int n = idx >> 8, k = idx & 255;
        val = (n < 128) ? lin_src_w[k * 128 + n] : lin_dst_w[k * 128 + (n - 128)];
    } else if (idx < 196608) {
        int r = idx - 65536;
        int l = r >> 15, e = r & 32767;
        int n = e >> 7, k = e & 127;
        val = mlp_w1[(size_t)l * 32768 + k * 256 + n];
    } else {
        int r = idx - 196608;
        int l = r >> 15, e = r & 32767;
        int n = e >> 8, k = e & 255;
        val = mlp_w2[(size_t)l * 32768 + k * 128 + n];
    }
    wt[idx] = f2bf(val);
}

// ---------------- x fp32 -> bf16 (one-time, vectorized) ----------------

__global__ __launch_bounds__(256) void xconv_kernel(const float* __restrict__ x,
                                                    unsigned short* __restrict__ xbf) {
    int idx = blockIdx.x * 256 + threadIdx.x;  // 8 elems per thread
    if (idx >= (Nn * Cc) / 8) return;
    const float4* p = (const float4*)(x) + (size_t)idx * 2;
    float4 v0 = p[0], v1 = p[1];
    unsigned short t[8];
    t[0] = f2bf(v0.x); t[1] = f2bf(v0.y); t[2] = f2bf(v0.z); t[3] = f2bf(v0.w);
    t[4] = f2bf(v1.x); t[5] = f2bf(v1.y); t[6] = f2bf(v1.z); t[7] = f2bf(v1.w);
    *(short8*)(xbf + (size_t)idx * 8) = *(short8*)t;
}

#define GLOAD16(gp, lp)                                                                       \
    __builtin_amdgcn_global_load_lds(                                                         \
        (const __attribute__((address_space(1))) unsigned int*)(gp),                          \
        (__attribute__((address_space(3))) unsigned int*)(lp), 16, 0, 0)

// ---------------- projection GEMM: xsd = x @ [Wsrc|Wdst] + [bsrc|bdst] ----------------
// 128x128 tile, BK=32, 4 waves, depth-2 prefetch (3 LDS buffers, counted vmcnt).
// Epilogue staged through LDS -> coalesced short8 stores.

__global__ __launch_bounds__(256) void proj_kernel(
    const unsigned short* __restrict__ A, const unsigned short* __restrict__ Bt,
    const float* __restrict__ bias, const float* __restrict__ bias2,
    unsigned short* __restrict__ Cout) {
    __shared__ __align__(16) unsigned short SH[24576];  // 48KB: 3xA(8KB) + 3xB(8KB); C reuse
    int tid = threadIdx.x;
    int wave = tid >> 6, lane = tid & 63;
    int wr = wave >> 1, wc = wave & 1;
    int lrow = lane & 15, quad = lane >> 4;
    int m0 = blockIdx.y * 128, n0 = blockIdx.x * 128;
    const int K = 256;

    const unsigned short* ag0 = A + (size_t)(m0 + (tid >> 2)) * K + (tid & 3) * 8;
    const unsigned short* ag1 = A + (size_t)(m0 + 64 + (tid >> 2)) * K + (tid & 3) * 8;
    const unsigned short* bg0 = Bt + (size_t)(n0 + (tid >> 2)) * K + (tid & 3) * 8;
    const unsigned short* bg1 = Bt + (size_t)(n0 + 64 + (tid >> 2)) * K + (tid & 3) * 8;

    f32x4 acc[4][4];
#pragma unroll
    for (int i = 0; i < 4; i++)
#pragma unroll
        for (int j = 0; j < 4; j++) acc[i][j] = (f32x4){0.f, 0.f, 0.f, 0.f};

    auto stage = [&](int buf, int koff) {
        GLOAD16(ag0 + koff, SH + buf * 4096 + wave * 512);
        GLOAD16(ag1 + koff, SH + buf * 4096 + 2048 + wave * 512);
        GLOAD16(bg0 + koff, SH + 12288 + buf * 4096 + wave * 512);
        GLOAD16(bg1 + koff, SH + 12288 + buf * 4096 + 2048 + wave * 512);
    };

    const int ntiles = 8;
    stage(0, 0);
    stage(1, 32);
    for (int t = 0; t < ntiles; ++t) {
        if (t + 1 < ntiles) {
            asm volatile("s_waitcnt vmcnt(4)\n\ts_barrier" ::: "memory");
        } else {
            asm volatile("s_waitcnt vmcnt(0)\n\ts_barrier" ::: "memory");
        }
        if (t + 2 < ntiles) stage((t + 2) % 3, (t + 2) * 32);
        int cur = t % 3;
        const unsigned short* As = SH + cur * 4096;
        const unsigned short* Bs = SH + 12288 + cur * 4096;
        short8 af[4], bfr[4];
#pragma unroll
        for (int mt = 0; mt < 4; mt++)
            af[mt] = *(const short8*)&As[(wr * 64 + mt * 16 + lrow) * 32 + quad * 8];
#pragma unroll
        for (int nf = 0; nf < 4; nf++)
            bfr[nf] = *(const short8*)&Bs[(wc * 64 + nf * 16 + lrow) * 32 + quad * 8];
#pragma unroll
        for (int mt = 0; mt < 4; mt++)
#pragma unroll
            for (int nf = 0; nf < 4; nf++)
                acc[mt][nf] = __builtin_amdgcn_mfma_f32_16x16x32_bf16(af[mt], bfr[nf],
                                                                     acc[mt][nf], 0, 0, 0);
    }

    __syncthreads();  // all frag reads done; reuse SH for C tile
    unsigned short* Cl = SH;  // [128][128] bf16 = 32KB
#pragma unroll
    for (int nf = 0; nf < 4; nf++) {
        int gc = n0 + wc * 64 + nf * 16 + lrow;
        float bs = (gc >= 128) ? bias2[gc - 128] : bias[gc];
        int col = wc * 64 + nf * 16 + lrow;
#pragma unroll
        for (int mt = 0; mt < 4; mt++)
#pragma unroll
            for (int r = 0; r < 4; r++)
                Cl[(wr * 64 + mt * 16 + quad * 4 + r) * 128 + col] = f2bf(acc[mt][nf][r] + bs);
    }
    __syncthreads();
#pragma unroll
    for (int p = 0; p < 8; p++) {
        int vid = p * 256 + tid;
        int row = vid >> 4, cg = (vid & 15) * 8;
        short8 v = *(const short8*)&Cl[row * 128 + cg];
        *(short8*)(Cout + (size_t)(m0 + row) * 256 + n0 + cg) = v;
    }
}

// ---------------- fused per-layer MLP: hbuf (+)= agg @ W1 -> BN -> ReLU -> @ W2 + b2,
//                  plus next-layer prenorm rbuf = bf16(relu(BN_pn(hbuf))) ----------------
// Per 64-node tile: phase 1 writes hmid to LDS only (never HBM); phase 2 consumes it.

__global__ __launch_bounds__(256) void mlp_kernel(
    const unsigned short* __restrict__ A,    // aggout [MPAD][128] bf16
    const unsigned short* __restrict__ W1,   // [256 n][128 k] bf16
    const unsigned short* __restrict__ W2,   // [128 n][256 k] bf16
    const float* __restrict__ b1, const float* __restrict__ bn_g,
    const float* __restrict__ bn_b, const float* __restrict__ bn_m,
    const float* __restrict__ bn_v, const float* __restrict__ b2,
    const float* __restrict__ pn_g, const float* __restrict__ pn_b,
    const float* __restrict__ pn_m, const float* __restrict__ pn_v,
    float* __restrict__ hbuf, unsigned short* __restrict__ rbuf, int rmw) {
    __shared__ __align__(16) unsigned short S[20480];    // 40KB: A1 dbuf 2x4KB @0, B1 dbuf 2x16KB @8KB
    __shared__ __align__(16) unsigned short Hm[64 * 264];  // hmid, padded rows (16B-aligned)

    int tid = threadIdx.x;
    int wave = tid >> 6, lane = tid & 63;
    int lrow = lane & 15, quad = lane >> 4;
    int m0 = blockIdx.x * 64;

    // ---- phase 1: Hm = relu(BN(A[m0:m0+64] @ W1 + b1))  (64x256) ----
    const unsigned short* ag = A + (size_t)(m0 + (tid >> 2)) * 128 + (tid & 3) * 8;
    const unsigned short* bg = W1 + (size_t)(tid >> 2) * 128 + (tid & 3) * 8;

    f32x4 acc1[4][4];
#pragma unroll
    for (int i = 0; i < 4; i++)
#pragma unroll
        for (int j = 0; j < 4; j++) acc1[i][j] = (f32x4){0.f, 0.f, 0.f, 0.f};

    auto stage1 = [&](int buf, int k0) {
        GLOAD16(ag + k0, S + buf * 2048 + wave * 512);
#pragma unroll
        for (int c = 0; c < 4; c++)
            GLOAD16(bg + (size_t)c * 64 * 128 + k0,
                    S + 4096 + buf * 8192 + c * 2048 + wave * 512);
    };

    stage1(0, 0);
    __syncthreads();
    for (int t = 0; t < 4; ++t) {
        if (t + 1 < 4) stage1((t + 1) & 1, (t + 1) * 32);
        int cur = t & 1;
        const unsigned short* A1s = S + cur * 2048;
        const unsigned short* B1s = S + 4096 + cur * 8192;
        short8 af[4], bfr[4];
#pragma unroll
        for (int mt = 0; mt < 4; mt++)
            af[mt] = *(const short8*)&A1s[(mt * 16 + lrow) * 32 + quad * 8];
#pragma unroll
        for (int nf = 0; nf < 4; nf++)
            bfr[nf] = *(const short8*)&B1s[(wave * 64 + nf * 16 + lrow) * 32 + quad * 8];
#pragma unroll
        for (int mt = 0; mt < 4; mt++)
#pragma unroll
            for (int nf = 0; nf < 4; nf++)
                acc1[mt][nf] = __builtin_amdgcn_mfma_f32_16x16x32_bf16(af[mt], bfr[nf],
                                                                      acc1[mt][nf], 0, 0, 0);
        __syncthreads();
    }

    // epilogue 1 -> Hm (LDS only)
#pragma unroll
    for (int nf = 0; nf < 4; nf++) {
        int gc = wave * 64 + nf * 16 + lrow;
        float bs = b1[gc];
        float g = bn_g[gc], bb = bn_b[gc], mm = bn_m[gc];
        float inv = rsqrtf(bn_v[gc] + 1e-5f);
#pragma unroll
        for (int mt = 0; mt < 4; mt++)
#pragma unroll
            for (int r = 0; r < 4; r++) {
                float v = acc1[mt][nf][r] + bs;
                v = fmaxf(g * (v - mm) * inv + bb, 0.f);
                Hm[(mt * 16 + quad * 4 + r) * 264 + gc] = f2bf(v);
            }
    }
    __syncthreads();  // Hm complete; phase-1 staging region free

    // ---- phase 2: C2 = Hm @ W2 + b2  (64x128) ----
    const unsigned short* b2g0 = W2 + (size_t)(tid >> 2) * 256 + (tid & 3) * 8;
    const unsigned short* b2g1 = W2 + (size_t)(64 + (tid >> 2)) * 256 + (tid & 3) * 8;

    f32x4 acc2[4][2];
#pragma unroll
    for (int i = 0; i < 4; i++)
#pragma unroll
        for (int j = 0; j < 2; j++) acc2[i][j] = (f32x4){0.f, 0.f, 0.f, 0.f};

    auto stage2 = [&](int buf, int k0) {
        GLOAD16(b2g0 + k0, S + buf * 4096 + wave * 512);
        GLOAD16(b2g1 + k0, S + buf * 4096 + 2048 + wave * 512);
    };

    stage2(0, 0);
    __syncthreads();
    for (int t = 0; t < 8; ++t) {
        if (t + 1 < 8) stage2((t + 1) & 1, (t + 1) * 32);
        int cur = t & 1;
        const unsigned short* B2s = S + cur * 4096;
        short8 af[4], bfr[2];
#pragma unroll
        for (int mt = 0; mt < 4; mt++)
            af[mt] = *(const short8*)&Hm[(mt * 16 + lrow) * 264 + t * 32 + quad * 8];
#pragma unroll
        for (int nf = 0; nf < 2; nf++)
            bfr[nf] = *(const short8*)&B2s[(wave * 32 + nf * 16 + lrow) * 32 + quad * 8];
#pragma unroll
        for (int mt = 0; mt < 4; mt++)
#pragma unroll
            for (int nf = 0; nf < 2; nf++)
                acc2[mt][nf] = __builtin_amdgcn_mfma_f32_16x16x32_bf16(af[mt], bfr[nf],
                                                                      acc2[mt][nf], 0, 0, 0);
        __syncthreads();
    }

    // epilogue 2: stage fp32 C2 in LDS (over staging region), then coalesced writeback
    float* C2 = (float*)S;  // [64][128] fp32 = 32KB
#pragma unroll
    for (int nf = 0; nf < 2; nf++) {
        int gc = wave * 32 + nf * 16 + lrow;
        float bs = b2[gc];
#pragma unroll
        for (int mt = 0; mt < 4; mt++)
#pragma unroll
            for (int r = 0; r < 4; r++)
                C2[(mt * 16 + quad * 4 + r) * 128 + gc] = acc2[mt][nf][r] + bs;
    }
    __syncthreads();
#pragma unroll
    for (int p = 0; p < 8; p++) {
        int vid = p * 256 + tid;
        int row = vid >> 5, c4 = (vid & 31) * 4;
        f32x4 v = *(const f32x4*)&C2[row * 128 + c4];
        float* hp = hbuf + (size_t)(m0 + row) * 128 + c4;
        if (rmw) v += *(const f32x4*)hp;
        *(f32x4*)hp = v;
        if (pn_g) {
            f32x4 pg = *(const f32x4*)&pn_g[c4];
            f32x4 pb = *(const f32x4*)&pn_b[c4];
            f32x4 pm = *(const f32x4*)&pn_m[c4];
            f32x4 pv = *(const f32x4*)&pn_v[c4];
            float r0 = fmaxf(pg[0] * (v[0] - pm[0]) * rsqrtf(pv[0] + 1e-5f) + pb[0], 0.f);
            float r1 = fmaxf(pg[1] * (v[1] - pm[1]) * rsqrtf(pv[1] + 1e-5f) + pb[1], 0.f);
            float r2 = fmaxf(pg[2] * (v[2] - pm[2]) * rsqrtf(pv[2] + 1e-5f) + pb[2], 0.f);
            float r3 = fmaxf(pg[3] * (v[3] - pm[3]) * rsqrtf(pv[3] + 1e-5f) + pb[3], 0.f);
            unsigned int w0 = (unsigned int)f2bf(r0) | ((unsigned int)f2bf(r1) << 16);
            unsigned int w1 = (unsigned int)f2bf(r2) | ((unsigned int)f2bf(r3) << 16);
            uint2 pk = make_uint2(w0, w1);
            *(uint2*)(rbuf + (size_t)(m0 + row) * 128 + c4) = pk;
        }
    }
}

// ---------------- Fused GENConv aggregation (scalarized control) ----------------
// One wave per dst node, 2 features per lane.  All wave-uniform values forced to
// SGPRs via readfirstlane: scalar loop control (s_cmp/s_branch, no exec masks),
// edge meta in SGPRs (uniform loads, candidates for s_load), gathers addressed as
// scalar-base + constant per-lane voffset (1 VALU op/gather instead of ~4).
// Per-edge +1e-7 dropped: softmax is invariant to the uniform z-shift and
// num' = num - 1e-7, so adding 1e-7 ONCE to the final quotient is exact.

template <int XSS>
__global__ __launch_bounds__(256) void agg_kernel(
    const unsigned short* __restrict__ xs,
    const unsigned short* __restrict__ xd, int xds,
    const int2* __restrict__ sedge, const int* __restrict__ off,
    const float* __restrict__ ew, const float* __restrict__ eb,
    const float* __restrict__ tptr, unsigned short* __restrict__ outb) {
    int wave = threadIdx.x >> 6;
    int lane = threadIdx.x & 63;
    int d = blockIdx.x * 4 + wave;  // Nn % 4 == 0, always < Nn
    int s0 = __builtin_amdgcn_readfirstlane(off[d]);
    int s1 = __builtin_amdgcn_readfirstlane(off[d + 1]);
    int f0 = lane * 2;
    unsigned int ud = *(const unsigned int*)(xd + (size_t)d * xds + f0);  // hoisted
    f32x2 wv = *(const f32x2*)(ew + f0);
    f32x2 bv = *(const f32x2*)(eb + f0);
    float c = tptr[0] * 1.44269504088896f;  // fold t and log2(e) into exp2 scale
    const f32x2 zz = {0.f, 0.f};
    f32x2 den = {0.f, 0.f}, num = {0.f, 0.f};

#define EDGE2(u, av)                                                \
    {                                                               \
        f32x2 xv = {bf2f_lo(u), bf2f_hi(u)};                        \
        f32x2 m = __builtin_elementwise_max(xv + bv + (av)*wv, zz); \
        f32x2 e;                                                    \
        e.x = __builtin_amdgcn_exp2f(m.x * c);                      \
        e.y = __builtin_amdgcn_exp2f(m.y * c);                      \
        den += e;                                                   \
        num += m * e;                                               \
    }
#define EDGE2M(u, av, mk)                                           \
    {                                                               \
        f32x2 xv = {bf2f_lo(u), bf2f_hi(u)};                        \
        f32x2 m = __builtin_elementwise_max(xv + bv + (av)*wv, zz); \
        f32x2 e;                                                    \
        e.x = __builtin_amdgcn_exp2f(m.x * c) * (mk);               \
        e.y = __builtin_amdgcn_exp2f(m.y * c) * (mk);               \
        den += e;                                                   \
        num += m * e;                                               \
    }

    int j = s0;
    for (; j + 8 <= s1; j += 8) {
        int4 q0 = *(const int4*)(sedge + j);      // uniform addr (j scalar)
        int4 q1 = *(const int4*)(sedge + j + 2);
        int4 q2 = *(const int4*)(sedge + j + 4);
        int4 q3 = *(const int4*)(sedge + j + 6);
        int i0 = __builtin_amdgcn_readfirstlane(q0.x);
        int i1 = __builtin_amdgcn_readfirstlane(q0.z);
        int i2 = __builtin_amdgcn_readfirstlane(q1.x);
        int i3 = __builtin_amdgcn_readfirstlane(q1.z);
        int i4 = __builtin_amdgcn_readfirstlane(q2.x);
        int i5 = __builtin_amdgcn_readfirstlane(q2.z);
        int i6 = __builtin_amdgcn_readfirstlane(q3.x);
        int i7 = __builtin_amdgcn_readfirstlane(q3.z);
        float a0 = __int_as_float(__builtin_amdgcn_readfirstlane(q0.y));
        float a1 = __int_as_float(__builtin_amdgcn_readfirstlane(q0.w));
        float a2 = __int_as_float(__builtin_amdgcn_readfirstlane(q1.y));
        float a3 = __int_as_float(__builtin_amdgcn_readfirstlane(q1.w));
        float a4 = __int_as_float(__builtin_amdgcn_readfirstlane(q2.y));
        float a5 = __int_as_float(__builtin_amdgcn_readfirstlane(q2.w));
        float a6 = __int_as_float(__builtin_amdgcn_readfirstlane(q3.y));
        float a7 = __int_as_float(__builtin_amdgcn_readfirstlane(q3.w));
        unsigned int u0 = *(const unsigned int*)(xs + (size_t)i0 * XSS + f0);
        unsigned int u1 = *(const unsigned int*)(xs + (size_t)i1 * XSS + f0);
        unsigned int u2 = *(const unsigned int*)(xs + (size_t)i2 * XSS + f0);
        unsigned int u3 = *(const unsigned int*)(xs + (size_t)i3 * XSS + f0);
        unsigned int u4 = *(const unsigned int*)(xs + (size_t)i4 * XSS + f0);
        unsigned int u5 = *(const unsigned int*)(xs + (size_t)i5 * XSS + f0);
        unsigned int u6 = *(const unsigned int*)(xs + (size_t)i6 * XSS + f0);
        unsigned int u7 = *(const unsigned int*)(xs + (size_t)i7 * XSS + f0);
        EDGE2(u0, a0)
        EDGE2(u1, a1)
        EDGE2(u2, a2)
        EDGE2(u3, a3)
        EDGE2(u4, a4)
        EDGE2(u5, a5)
        EDGE2(u6, a6)
        EDGE2(u7, a7)
    }
    if (j < s1) {  // masked batch: scalar clamp to last valid edge, zero masked
        int last = s1 - 1;  // s1 > s0 >= 0 here
        int ii[8];
        float aa[8], mk[8];
#pragma unroll
        for (int k = 0; k < 8; k++) {
            int jj = j + k;                 // scalar
            int cl = (jj < s1) ? jj : last; // scalar select
            int2 p = sedge[cl];             // uniform load
            ii[k] = __builtin_amdgcn_readfirstlane(p.x);
            aa[k] = __int_as_float(__builtin_amdgcn_readfirstlane(p.y));
            mk[k] = (jj < s1) ? 1.f : 0.f;  // scalar
        }
        unsigned int uu[8];
#pragma unroll
        for (int k = 0; k < 8; k++)
            uu[k] = *(const unsigned int*)(xs + (size_t)ii[k] * XSS + f0);
#pragma unroll
        for (int k = 0; k < 8; k++) EDGE2M(uu[k], aa[k], mk[k])
    }
#undef EDGE2
#undef EDGE2M
    // den >= 1 whenever deg > 0 (each e = exp2(m*c) >= 1 for m >= 0)
    float a0 = (s1 > s0) ? (num.x / den.x + 1e-7f) : 0.f;
    float a1 = (s1 > s0) ? (num.y / den.y + 1e-7f) : 0.f;
    unsigned int lo = f2bf(a0 + bf2f_lo(ud));
    unsigned int hi = f2bf(a1 + bf2f_hi(ud));
    *(unsigned int*)(outb + (size_t)d * Hh + f0) = lo | (hi << 16);
}

// ---------------- final norm + hierarchical mean-pool ----------------

#define PCHUNK 100

__global__ __launch_bounds__(128) void pool_kernel(
    const float* __restrict__ h, const int* __restrict__ batch,
    const float* __restrict__ g, const float* __restrict__ b,
    const float* __restrict__ m, const float* __restrict__ v,
    float* __restrict__ pooled, float* __restrict__ cnt) {
    int hh = threadIdx.x;
    int i0 = blockIdx.x * PCHUNK;
    int i1 = min(i0 + PCHUNK, Nn);
    if (i0 >= Nn) return;
    float gg = g[hh], bb = b[hh], mm = m[hh], inv = rsqrtf(v[hh] + 1e-5f);
    int cur = batch[i0];
    float sum = 0.f, c = 0.f;
    for (int i = i0; i < i1; i++) {
        int gid = batch[i];
        float val = fmaxf(gg * (h[(size_t)i * Hh + hh] - mm) * inv + bb, 0.f);
        if (gid != cur) {
            atomicAdd(&pooled[(size_t)cur * Hh + hh], sum);
            if (hh == 0) atomicAdd(&cnt[cur], c);
            cur = gid;
            sum = 0.f;
            c = 0.f;
        }
        sum += val;
        c += 1.f;
    }
    atomicAdd(&pooled[(size_t)cur * Hh + hh], sum);
    if (hh == 0) atomicAdd(&cnt[cur], c);
}

// ---------------- classifier ----------------

__global__ __launch_bounds__(128) void cls_kernel(const float* __restrict__ pooled,
                                                  const float* __restrict__ cnt,
                                                  const float* __restrict__ clinical,
                                                  const float* __restrict__ w,
                                                  const float* __restrict__ bias,
                                                  float* __restrict__ out) {
    int t = threadIdx.x;
    int g = t >> 1, c = t & 1;
    float inv = 1.f / fmaxf(cnt[g], 1.f);
    float s = bias[c];
    for (int j = 0; j < Hh; j++) s += pooled[g * Hh + j] * inv * w[j * NCc + c];
    for (int k = 0; k < Kk; k++) s += clinical[g * Kk + k] * w[(Hh + k) * NCc + c];
    out[g * NCc + c] = s;
}

// ---------------- launch ----------------

extern "C" void kernel_launch(void* const* d_in, const int* in_sizes, int n_in,
                              void* d_out, int out_size, void* d_ws, size_t ws_size,
                              hipStream_t stream) {
    const float* x = (const float*)d_in[0];
    const int* eidx = (const int*)d_in[1];
    const float* eattr = (const float*)d_in[2];
    const int* batch = (const int*)d_in[3];
    const float* clinical = (const float*)d_in[4];
    const float* lin_src_w = (const float*)d_in[5];
    const float* lin_src_b = (const float*)d_in[6];
    const float* lin_dst_w = (const float*)d_in[7];
    const float* lin_dst_b = (const float*)d_in[8];
    const float* edge_w = (const float*)d_in[9];
    const float* edge_b = (const float*)d_in[10];
    const float* tt = (const float*)d_in[11];
    const float* mlp_w1 = (const float*)d_in[12];
    const float* mlp_b1 = (const float*)d_in[13];
    const float* bn_g = (const float*)d_in[14];
    const float* bn_b = (const float*)d_in[15];
    const float* bn_m = (const float*)d_in[16];
    const float* bn_v = (const float*)d_in[17];
    const float* mlp_w2 = (const float*)d_in[18];
    const float* mlp_b2 = (const float*)d_in[19];
    const float* norm_g = (const float*)d_in[20];
    const float* norm_b = (const float*)d_in[21];
    const float* norm_m = (const float*)d_in[22];
    const float* norm_v = (const float*)d_in[23];
    const float* cls_w = (const float*)d_in[24];
    const float* cls_b = (const float*)d_in[25];
    float* out = (float*)d_out;

    const int* src = eidx;
    const int* dst = eidx + Ee;

    char* ws = (char*)d_ws;
    size_t off_b = 0;
    auto alloc = [&](size_t bytes) -> void* {
        void* p = ws + off_b;
        off_b += (bytes + 255) & ~(size_t)255;
        return p;
    };
    // All GEMM-touched buffers padded to MPAD rows (garbage pad rows never read).
    unsigned short* xsd = (unsigned short*)alloc((size_t)MPAD * 256 * 2);   // proj out
    unsigned short* rbuf = (unsigned short*)alloc((size_t)MPAD * Hh * 2);   // prenorm out
    unsigned short* aggout = (unsigned short*)alloc((size_t)MPAD * Hh * 2);
    unsigned short* xbf = (unsigned short*)alloc((size_t)MPAD * 256 * 2);
    float* hbuf = (float*)alloc((size_t)MPAD * Hh * 4);
    int* deg = (int*)alloc((Nn + 1) * 4);
    int* offp = (int*)alloc((Nn + 1) * 4);
    int* pos = (int*)alloc((size_t)Nn * 4);
    int* bsum = (int*)alloc(NB * 4);
    int* boff = (int*)alloc(NB * 4);
    int2* sedge = (int2*)alloc((size_t)Ee * 8);
    float* pooled = (float*)alloc((size_t)Gg * Hh * 4);
    float* cntb = (float*)alloc(Gg * 4);
    unsigned short* wt = (unsigned short*)alloc((size_t)327680 * 2);

    hipMemsetAsync(deg, 0, (Nn + 1) * 4, stream);
    hipMemsetAsync(pooled, 0, (size_t)Gg * Hh * 4, stream);
    hipMemsetAsync(cntb, 0, Gg * 4, stream);

    hist_kernel<<<(Ee + 255) / 256, 256, 0, stream>>>(dst, deg);
    bsum_kernel<<<NB, 256, 0, stream>>>(deg, bsum);
    bscan_kernel<<<1, 256, 0, stream>>>(bsum, boff, offp);
    offsets_kernel<<<NB, 256, 0, stream>>>(deg, boff, offp, pos);
    scatter_kernel<<<(Ee + 255) / 256, 256, 0, stream>>>(src, dst, eattr, pos, sedge);
    wconv_kernel<<<1280, 256, 0, stream>>>(lin_src_w, lin_dst_w, mlp_w1, mlp_w2, wt);
    xconv_kernel<<<(Nn * Cc / 8 + 255) / 256, 256, 0, stream>>>(x, xbf);

    const unsigned short* wt_proj = wt;
    const unsigned short* wt_w1 = wt + 65536;
    const unsigned short* wt_w2 = wt + 196608;

    // Fused projection: xsd[:, :128] = x@Wsrc+b, xsd[:, 128:] = x@Wdst+b
    dim3 gproj(2, MPAD / 128);
    proj_kernel<<<gproj, 256, 0, stream>>>(xbf, wt_proj, lin_src_b, lin_dst_b, xsd);

    for (int l = 0; l < Ll; l++) {
        if (l == 0) {
            agg_kernel<256><<<Nn / 4, 256, 0, stream>>>(xsd, xsd + 128, 256, sedge, offp,
                                                        edge_w + l * Hh, edge_b + l * Hh,
                                                        tt + l, aggout);
        } else {
            agg_kernel<128><<<Nn / 4, 256, 0, stream>>>(rbuf, rbuf, Hh, sedge, offp,
                                                        edge_w + l * Hh, edge_b + l * Hh,
                                                        tt + l, aggout);
        }
        const float* png = (l < Ll - 1) ? (norm_g + (l + 1) * Hh) : nullptr;
        const float* pnb = (l < Ll - 1) ? (norm_b + (l + 1) * Hh) : nullptr;
        const float* pnm = (l < Ll - 1) ? (norm_m + (l + 1) * Hh) : nullptr;
        const float* pnv = (l < Ll - 1) ? (norm_v + (l + 1) * Hh) : nullptr;
        mlp_kernel<<<MPAD / 64, 256, 0, stream>>>(
            aggout, wt_w1 + (size_t)l * 32768, wt_w2 + (size_t)l * 32768,
            mlp_b1 + l * 2 * Hh, bn_g + l * 2 * Hh, bn_b + l * 2 * Hh,
            bn_m + l * 2 * Hh, bn_v + l * 2 * Hh, mlp_b2 + l * Hh,
            png, pnb, pnm, pnv, hbuf, rbuf, (l == 0) ? 0 : 1);
    }

    pool_kernel<<<(Nn + PCHUNK - 1) / PCHUNK, 128, 0, stream>>>(hbuf, batch, norm_g, norm_b,
                                                                norm_m, norm_v, pooled, cntb);
    cls_kernel<<<1, 128, 0, stream>>>(pooled, cntb, clinical, cls_w, cls_b, out);
}